// Round 5
// baseline (150.714 us; speedup 1.0000x reference)
//
#include <hip/hip_runtime.h>
#include <math.h>

constexpr int D    = 128;
constexpr int BT   = 128;    // targets per bucket (bucket = tgt >> 7)
constexpr int TILE = 4096;   // edges per bucketize block

using bf16x8 = __attribute__((ext_vector_type(8))) short;
using f32x4  = __attribute__((ext_vector_type(4))) float;
#define MFMA16 __builtin_amdgcn_mfma_f32_16x16x32_bf16

__device__ __forceinline__ unsigned short f2bf(float f) {
    unsigned u = __builtin_bit_cast(unsigned, f);
    u = (u + 0x7FFF + ((u >> 16) & 1)) >> 16;   // RNE
    return (unsigned short)u;
}

// ---------------------------------------------------------------------------
// prep: fused by block range.
//   [0, GA+GB)        : bucketize edges (LDS histogram -> coalesced runs)
//   [GA+GB, +GCONV)   : x f32 row-major -> x_bfs bf16 SLICE-major [4][N][32]
//   [GA+GB+GCONV,+24) : repack weights -> MFMA B-fragment order
// ---------------------------------------------------------------------------
__global__ __launch_bounds__(256)
void prep_kernel(const float* __restrict__ x, unsigned short* __restrict__ x_bfs,
                 const int* __restrict__ ea, int Ea,
                 const int* __restrict__ eb, int Eb,
                 unsigned int* __restrict__ ent_a, int* __restrict__ cnt_a,
                 unsigned int* __restrict__ ent_b, int* __restrict__ cnt_b,
                 const float* __restrict__ Wl, const float* __restrict__ Wr,
                 const float* __restrict__ Wp,
                 unsigned short* __restrict__ WlB, unsigned short* __restrict__ WrB,
                 unsigned short* __restrict__ WpB,
                 int N, int NBKT, int CAP, int GA, int GB, int GCONV)
{
    __shared__ int hist[512];
    __shared__ int base[512];

    const int bid = blockIdx.x;
    const int t   = threadIdx.x;

    if (bid < GA + GB) {
        // ---- bucketize ----
        const int type = (bid >= GA);
        const int* e   = type ? eb : ea;
        const int  E   = type ? Eb : Ea;
        unsigned int* ent = type ? ent_b : ent_a;
        int* cnt          = type ? cnt_b : cnt_a;
        const int i0 = (bid - type * GA) * TILE;

        for (int h = t; h < NBKT; h += 256) hist[h] = 0;
        __syncthreads();

        int tgts[16];
        #pragma unroll
        for (int j = 0; j < 16; ++j) {
            int i = i0 + j * 256 + t;
            tgts[j] = (i < E) ? e[(size_t)E + i] : -1;
            if (tgts[j] >= 0) atomicAdd(&hist[tgts[j] >> 7], 1);
        }
        __syncthreads();

        for (int h = t; h < NBKT; h += 256) {
            base[h] = (hist[h] > 0) ? atomicAdd(&cnt[h], hist[h]) : 0;
            hist[h] = 0;
        }
        __syncthreads();

        #pragma unroll
        for (int j = 0; j < 16; ++j) {
            int i = i0 + j * 256 + t;
            if (tgts[j] >= 0) {
                int b   = tgts[j] >> 7;
                int pos = base[b] + atomicAdd(&hist[b], 1);
                if (pos < CAP)
                    ent[(size_t)b * CAP + pos] = ((unsigned)e[i] << 7) | (tgts[j] & 127);
            }
        }
    } else if (bid < GA + GB + GCONV) {
        // ---- convert: slice-major x_bfs[s][n][c], s = col>>5 ----
        const int total4 = N * 32;            // float4s
        for (int i = (bid - GA - GB) * 256 + t; i < total4; i += GCONV * 256) {
            int n  = i >> 5;
            int j4 = i & 31;
            float4 v = reinterpret_cast<const float4*>(x)[i];
            ushort4 o;
            o.x = f2bf(v.x); o.y = f2bf(v.y); o.z = f2bf(v.z); o.w = f2bf(v.w);
            int s = j4 >> 3, c = (j4 & 7) * 4;
            *reinterpret_cast<ushort4*>(x_bfs + ((size_t)s * N + n) * 32 + c) = o;
        }
    } else {
        // ---- repack weights ----
        int gw = ((bid - GA - GB - GCONV) * 256 + t) >> 6;   // 0..95
        int l  = t & 63;
        const float* W = (gw < 32) ? Wl : (gw < 64) ? Wr : Wp;
        unsigned short* O = (gw < 32) ? WlB : (gw < 64) ? WrB : WpB;
        int ktnt = gw & 31, kt = ktnt >> 3, nt = ktnt & 7;
        bf16x8 v;
        #pragma unroll
        for (int j = 0; j < 8; ++j)
            v[j] = (short)f2bf(W[(size_t)(kt * 32 + (l >> 4) * 8 + j) * D + nt * 16 + (l & 15)]);
        *reinterpret_cast<bf16x8*>(O + ((size_t)ktnt * 64 + l) * 8) = v;
    }
}

// ---------------------------------------------------------------------------
// sort: per (type,bucket): entries -> LDS histogram + scan + scatter, persist
// sorted src list (ushort, coalesced) + per-node offsets for the gather pass.
// ---------------------------------------------------------------------------
__global__ __launch_bounds__(512)
void sort_kernel(const unsigned int* __restrict__ ent_a, const int* __restrict__ cnt_a,
                 const unsigned int* __restrict__ ent_b, const int* __restrict__ cnt_b,
                 unsigned short* __restrict__ srcl_g, int* __restrict__ off_g,
                 int NBKT, int CAP)
{
    extern __shared__ __align__(16) char smem_raw[];
    int* tmp  = (int*)smem_raw;                          // CAP
    int* off  = tmp + CAP;                               // BT+1
    int* cur  = off + BT + 1;                            // BT
    int* wtot = cur + BT;                                // 2
    unsigned short* srcl = (unsigned short*)(wtot + 2);  // CAP

    const int bid  = blockIdx.x;
    const int type = (bid >= NBKT);
    const int k    = bid - type * NBKT;
    const unsigned int* ent = type ? ent_b : ent_a;
    const int cnt = min((type ? cnt_b : cnt_a)[k], CAP);

    const int t = threadIdx.x, l = t & 63, w = t >> 6;

    if (t < BT) off[t] = 0;
    __syncthreads();

    for (int i = t; i < cnt; i += 512) {
        unsigned e = ent[(size_t)k * CAP + i];
        tmp[i] = (int)e;
        atomicAdd(&off[e & (BT - 1)], 1);
    }
    __syncthreads();

    int v = 0, s = 0;
    if (t < BT) {
        v = off[t]; s = v;
        #pragma unroll
        for (int o = 1; o < 64; o <<= 1) {
            int u = __shfl_up(s, o, 64);
            if (l >= o) s += u;
        }
        if (l == 63) wtot[w] = s;
    }
    __syncthreads();
    if (t < BT) {
        int ex = ((w == 1) ? wtot[0] : 0) + s - v;
        off[t] = ex; cur[t] = ex;
    }
    if (t == 0) off[BT] = wtot[0] + wtot[1];
    __syncthreads();

    for (int i = t; i < cnt; i += 512) {
        unsigned e = (unsigned)tmp[i];
        int pos = atomicAdd(&cur[e & (BT - 1)], 1);
        srcl[pos] = (unsigned short)(e >> 7);
    }
    __syncthreads();

    for (int i = t; i < cnt; i += 512)
        srcl_g[(size_t)bid * CAP + i] = srcl[i];
    if (t <= BT)
        off_g[(size_t)bid * (BT + 1) + t] = off[t];
}

// ---------------------------------------------------------------------------
// gather: grid = 4 slices x 2 types x NBKT.  slice = bid & 3 -> under the
// bid%8 -> XCD round-robin each XCD touches ONE 3.2 MB slice (L2-resident).
// 4-lane-quads process 4 edges concurrently; lane = 16 x ushort2 per edge
// (64 B coalesced); quad partials reduced via shfl_xor(16,32).
// ---------------------------------------------------------------------------
__global__ __launch_bounds__(256)
void gather_kernel(const unsigned short* __restrict__ x_bfs,
                   const unsigned short* __restrict__ srcl_g,
                   const int* __restrict__ off_g,
                   unsigned short* __restrict__ mean_a_s,
                   unsigned short* __restrict__ mean_b_s,
                   int N, int NBKT, int CAP)
{
    extern __shared__ __align__(16) char smem_raw[];
    int* off = (int*)smem_raw;                           // BT+1
    unsigned short* srcl = (unsigned short*)(off + BT + 1);  // CAP

    const int bid   = blockIdx.x;
    const int slice = bid & 3;
    const int tb    = bid >> 2;                // (type,bucket)
    const int type  = (tb >= NBKT);
    const int k     = tb - type * NBKT;

    const int t = threadIdx.x, l = t & 63, w = t >> 6;
    const int q = l >> 4, c = l & 15;

    const int cnt = off_g[(size_t)tb * (BT + 1) + BT];
    for (int i = t; i <= BT; i += 256)
        off[i] = off_g[(size_t)tb * (BT + 1) + i];
    for (int i = t; i < cnt; i += 256)
        srcl[i] = srcl_g[(size_t)tb * CAP + i];
    __syncthreads();

    const unsigned short* xs = x_bfs + (size_t)slice * N * 32;
    unsigned short* mean = (type ? mean_b_s : mean_a_s) + (size_t)slice * N * 32;

    for (int tt = w; tt < BT; tt += 4) {
        const int n = k * BT + tt;
        if (n >= N) break;
        const int o0 = off[tt], o1 = off[tt + 1];
        float ax = 0.f, ay = 0.f;

        int j = o0 + q;
        for (; j + 4 < o1; j += 8) {
            int s0 = srcl[j], s1 = srcl[j + 4];
            unsigned v0 = *(const unsigned*)(xs + (size_t)s0 * 32 + c * 2);
            unsigned v1 = *(const unsigned*)(xs + (size_t)s1 * 32 + c * 2);
            ax += __builtin_bit_cast(float, v0 << 16)
                + __builtin_bit_cast(float, v1 << 16);
            ay += __builtin_bit_cast(float, v0 & 0xffff0000u)
                + __builtin_bit_cast(float, v1 & 0xffff0000u);
        }
        if (j < o1) {
            int s0 = srcl[j];
            unsigned v0 = *(const unsigned*)(xs + (size_t)s0 * 32 + c * 2);
            ax += __builtin_bit_cast(float, v0 << 16);
            ay += __builtin_bit_cast(float, v0 & 0xffff0000u);
        }

        ax += __shfl_xor(ax, 16, 64); ax += __shfl_xor(ax, 32, 64);
        ay += __shfl_xor(ay, 16, 64); ay += __shfl_xor(ay, 32, 64);

        float r = 1.0f / fmaxf((float)(o1 - o0), 1.0f);
        if (q == 0) {
            unsigned o = ((unsigned)f2bf(ay * r) << 16) | f2bf(ax * r);
            *(unsigned*)(mean + (size_t)n * 32 + c * 2) = o;
        }
    }
}

// ---------------------------------------------------------------------------
// MFMA GEMM (round-3 structure; A-fragment loads adapted to slice-major).
// ---------------------------------------------------------------------------
__global__ __launch_bounds__(256)
void gemm_kernel(const unsigned short* __restrict__ mean_a_s,
                 const unsigned short* __restrict__ mean_b_s,
                 const unsigned short* __restrict__ x_bfs,
                 const unsigned short* __restrict__ WlB,
                 const unsigned short* __restrict__ WrB,
                 const unsigned short* __restrict__ WpB,
                 const float* __restrict__ bl, const float* __restrict__ bp,
                 float* __restrict__ out, int N)
{
    __shared__ unsigned short hA[64 * D];
    __shared__ unsigned short hB[64 * D];

    const int t = threadIdx.x, w = t >> 6, l = t & 63;
    const int q = l & 15;
    const int kg = l >> 4;
    const int node0 = blockIdx.x * 64 + w * 16;
    const int arow = min(node0 + q, N - 1);

    bf16x8 fa[4], fb[4], fx[4];
    #pragma unroll
    for (int kt = 0; kt < 4; ++kt) {
        size_t o = ((size_t)kt * N + arow) * 32 + kg * 8;   // slice kt, cols kg*8..
        fa[kt] = *reinterpret_cast<const bf16x8*>(mean_a_s + o);
        fb[kt] = *reinterpret_cast<const bf16x8*>(mean_b_s + o);
        fx[kt] = *reinterpret_cast<const bf16x8*>(x_bfs + o);
    }

    #pragma unroll
    for (int nt = 0; nt < 8; ++nt) {
        f32x4 ca = {0.f, 0.f, 0.f, 0.f};
        f32x4 cb = {0.f, 0.f, 0.f, 0.f};
        #pragma unroll
        for (int kt = 0; kt < 4; ++kt) {
            const size_t fo = ((size_t)(kt * 8 + nt) * 64 + l) * 8;
            bf16x8 wl = *reinterpret_cast<const bf16x8*>(WlB + fo);
            bf16x8 wr = *reinterpret_cast<const bf16x8*>(WrB + fo);
            ca = MFMA16(fa[kt], wl, ca, 0, 0, 0);
            ca = MFMA16(fx[kt], wr, ca, 0, 0, 0);
            cb = MFMA16(fb[kt], wl, cb, 0, 0, 0);
            cb = MFMA16(fx[kt], wr, cb, 0, 0, 0);
        }
        float blv = bl[nt * 16 + q];
        #pragma unroll
        for (int r = 0; r < 4; ++r) {
            int lrow = w * 16 + kg * 4 + r;
            int byte = lrow * 256 + (nt * 16 + q) * 2;
            byte ^= ((lrow & 7) << 4);
            *reinterpret_cast<unsigned short*>(reinterpret_cast<char*>(hA) + byte) = f2bf(ca[r] + blv);
            *reinterpret_cast<unsigned short*>(reinterpret_cast<char*>(hB) + byte) = f2bf(cb[r] + blv);
        }
    }
    __syncthreads();

    bf16x8 ga[4], gb[4];
    #pragma unroll
    for (int kt = 0; kt < 4; ++kt) {
        int lrow = w * 16 + q;
        int byte = lrow * 256 + kt * 64 + kg * 16;
        byte ^= ((lrow & 7) << 4);
        ga[kt] = *reinterpret_cast<bf16x8*>(reinterpret_cast<char*>(hA) + byte);
        gb[kt] = *reinterpret_cast<bf16x8*>(reinterpret_cast<char*>(hB) + byte);
    }

    f32x4 la[8], lb[8];
    #pragma unroll
    for (int nt = 0; nt < 8; ++nt) {
        la[nt] = f32x4{0.f, 0.f, 0.f, 0.f};
        lb[nt] = f32x4{0.f, 0.f, 0.f, 0.f};
        #pragma unroll
        for (int kt = 0; kt < 4; ++kt) {
            const size_t fo = ((size_t)(kt * 8 + nt) * 64 + l) * 8;
            bf16x8 wp = *reinterpret_cast<const bf16x8*>(WpB + fo);
            la[nt] = MFMA16(ga[kt], wp, la[nt], 0, 0, 0);
            lb[nt] = MFMA16(gb[kt], wp, lb[nt], 0, 0, 0);
        }
        float bpv = bp[nt * 16 + q];
        #pragma unroll
        for (int r = 0; r < 4; ++r) { la[nt][r] += bpv; lb[nt][r] += bpv; }
    }

    #pragma unroll
    for (int r = 0; r < 4; ++r) {
        float ma = -INFINITY, mb = -INFINITY;
        #pragma unroll
        for (int nt = 0; nt < 8; ++nt) {
            ma = fmaxf(ma, la[nt][r]);
            mb = fmaxf(mb, lb[nt][r]);
        }
        #pragma unroll
        for (int o = 1; o < 16; o <<= 1) {
            ma = fmaxf(ma, __shfl_xor(ma, o, 64));
            mb = fmaxf(mb, __shfl_xor(mb, o, 64));
        }
        float ea[8], eb[8], sa = 0.f, sb = 0.f;
        #pragma unroll
        for (int nt = 0; nt < 8; ++nt) {
            ea[nt] = __expf(la[nt][r] - ma); sa += ea[nt];
            eb[nt] = __expf(lb[nt][r] - mb); sb += eb[nt];
        }
        #pragma unroll
        for (int o = 1; o < 16; o <<= 1) {
            sa += __shfl_xor(sa, o, 64);
            sb += __shfl_xor(sb, o, 64);
        }
        float ra = 0.5f / sa, rb = 0.5f / sb;
        int grow = node0 + kg * 4 + r;
        if (grow < N) {
            float* o = out + (size_t)grow * D + q;
            #pragma unroll
            for (int nt = 0; nt < 8; ++nt)
                o[nt * 16] = ea[nt] * ra + eb[nt] * rb;
        }
    }
}

// ---------------------------------------------------------------------------
extern "C" void kernel_launch(void* const* d_in, const int* in_sizes, int n_in,
                              void* d_out, int out_size, void* d_ws, size_t ws_size,
                              hipStream_t stream)
{
    const float* x  = (const float*)d_in[0];
    const float* Wl = (const float*)d_in[1];
    const float* bl = (const float*)d_in[2];
    const float* Wr = (const float*)d_in[3];
    const float* Wp = (const float*)d_in[4];
    const float* bp = (const float*)d_in[5];
    const int*   ea = (const int*)d_in[6];
    const int*   eb = (const int*)d_in[7];

    const int N  = in_sizes[0] / D;
    const int Ea = in_sizes[6] / 2;
    const int Eb = in_sizes[7] / 2;

    const int NBKT = (N + BT - 1) / BT;
    const int Emax = Ea > Eb ? Ea : Eb;
    int CAP = (int)(((long long)Emax * BT / N) * 5 / 4 + 128);
    CAP = (CAP + 7) & ~7;                                   // keep alignment even

    unsigned int* ent_a = (unsigned int*)d_ws;              // NBKT*CAP
    unsigned int* ent_b = ent_a + (size_t)NBKT * CAP;
    int* cnt_a = (int*)(ent_b + (size_t)NBKT * CAP);        // NBKT
    int* cnt_b = cnt_a + NBKT;
    int* off_g = cnt_b + NBKT;                              // 2*NBKT*(BT+1)
    uintptr_t p = (uintptr_t)(off_g + (size_t)2 * NBKT * (BT + 1));
    p = (p + 15) & ~(uintptr_t)15;
    unsigned short* srcl_g  = (unsigned short*)p;           // 2*NBKT*CAP
    unsigned short* x_bfs   = srcl_g + (size_t)2 * NBKT * CAP;
    unsigned short* mean_a_s = x_bfs + (size_t)N * D;
    unsigned short* mean_b_s = mean_a_s + (size_t)N * D;
    unsigned short* WlB     = mean_b_s + (size_t)N * D;
    unsigned short* WrB     = WlB + D * D;
    unsigned short* WpB     = WrB + D * D;

    hipMemsetAsync(cnt_a, 0, sizeof(int) * 2 * (size_t)NBKT, stream);

    const int GA = (Ea + TILE - 1) / TILE;
    const int GB = (Eb + TILE - 1) / TILE;
    const int GCONV = 512;
    prep_kernel<<<GA + GB + GCONV + 24, 256, 0, stream>>>(
        x, x_bfs, ea, Ea, eb, Eb, ent_a, cnt_a, ent_b, cnt_b,
        Wl, Wr, Wp, WlB, WrB, WpB, N, NBKT, CAP, GA, GB, GCONV);

    const int smem_sort = CAP * 6 + (BT + 1 + BT + 2) * 4 + 16;
    sort_kernel<<<2 * NBKT, 512, smem_sort, stream>>>(
        ent_a, cnt_a, ent_b, cnt_b, srcl_g, off_g, NBKT, CAP);

    const int smem_gather = (BT + 1) * 4 + CAP * 2 + 16;
    gather_kernel<<<8 * NBKT, 256, smem_gather, stream>>>(
        x_bfs, srcl_g, off_g, mean_a_s, mean_b_s, N, NBKT, CAP);

    gemm_kernel<<<(N + 63) / 64, 256, 0, stream>>>(
        mean_a_s, mean_b_s, x_bfs, WlB, WrB, WpB, bl, bp, (float*)d_out, N);
}

// Round 6
// 148.471 us; speedup vs baseline: 1.0151x; 1.0151x over previous
//
#include <hip/hip_runtime.h>
#include <math.h>

constexpr int D    = 128;
constexpr int BT   = 128;    // targets per bucket (bucket = tgt >> 7)
constexpr int TILE = 4096;   // edges per bucketize block

using bf16x8 = __attribute__((ext_vector_type(8))) short;
using f32x4  = __attribute__((ext_vector_type(4))) float;
using f32x2  = __attribute__((ext_vector_type(2))) float;
#define MFMA16 __builtin_amdgcn_mfma_f32_16x16x32_bf16

__device__ __forceinline__ unsigned short f2bf(float f) {
    unsigned u = __builtin_bit_cast(unsigned, f);
    u = (u + 0x7FFF + ((u >> 16) & 1)) >> 16;   // RNE
    return (unsigned short)u;
}

// ---------------------------------------------------------------------------
// prep: fused by block range.
//   [0, GA+GB)        : bucketize edges (LDS histogram -> coalesced runs)
//   [GA+GB, +GCONV)   : x f32 row-major -> x_bfs bf16 SLICE-major [4][N][32]
//   [GA+GB+GCONV,+24) : repack weights -> MFMA B-fragment order
// ---------------------------------------------------------------------------
__global__ __launch_bounds__(256)
void prep_kernel(const float* __restrict__ x, unsigned short* __restrict__ x_bfs,
                 const int* __restrict__ ea, int Ea,
                 const int* __restrict__ eb, int Eb,
                 unsigned int* __restrict__ ent_a, int* __restrict__ cnt_a,
                 unsigned int* __restrict__ ent_b, int* __restrict__ cnt_b,
                 const float* __restrict__ Wl, const float* __restrict__ Wr,
                 const float* __restrict__ Wp,
                 unsigned short* __restrict__ WlB, unsigned short* __restrict__ WrB,
                 unsigned short* __restrict__ WpB,
                 int N, int NBKT, int CAP, int GA, int GB, int GCONV)
{
    __shared__ int hist[512];
    __shared__ int base[512];

    const int bid = blockIdx.x;
    const int t   = threadIdx.x;

    if (bid < GA + GB) {
        // ---- bucketize ----
        const int type = (bid >= GA);
        const int* e   = type ? eb : ea;
        const int  E   = type ? Eb : Ea;
        unsigned int* ent = type ? ent_b : ent_a;
        int* cnt          = type ? cnt_b : cnt_a;
        const int i0 = (bid - type * GA) * TILE;

        for (int h = t; h < NBKT; h += 256) hist[h] = 0;
        __syncthreads();

        int tgts[16];
        #pragma unroll
        for (int j = 0; j < 16; ++j) {
            int i = i0 + j * 256 + t;
            tgts[j] = (i < E) ? e[(size_t)E + i] : -1;
            if (tgts[j] >= 0) atomicAdd(&hist[tgts[j] >> 7], 1);
        }
        __syncthreads();

        for (int h = t; h < NBKT; h += 256) {
            base[h] = (hist[h] > 0) ? atomicAdd(&cnt[h], hist[h]) : 0;
            hist[h] = 0;
        }
        __syncthreads();

        #pragma unroll
        for (int j = 0; j < 16; ++j) {
            int i = i0 + j * 256 + t;
            if (tgts[j] >= 0) {
                int b   = tgts[j] >> 7;
                int pos = base[b] + atomicAdd(&hist[b], 1);
                if (pos < CAP)
                    ent[(size_t)b * CAP + pos] = ((unsigned)e[i] << 7) | (tgts[j] & 127);
            }
        }
    } else if (bid < GA + GB + GCONV) {
        // ---- convert: slice-major x_bfs[s][n][c], s = col>>5 ----
        const int total4 = N * 32;            // float4s
        for (int i = (bid - GA - GB) * 256 + t; i < total4; i += GCONV * 256) {
            int n  = i >> 5;
            int j4 = i & 31;
            float4 v = reinterpret_cast<const float4*>(x)[i];
            ushort4 o;
            o.x = f2bf(v.x); o.y = f2bf(v.y); o.z = f2bf(v.z); o.w = f2bf(v.w);
            int s = j4 >> 3, c = (j4 & 7) * 4;
            *reinterpret_cast<ushort4*>(x_bfs + ((size_t)s * N + n) * 32 + c) = o;
        }
    } else {
        // ---- repack weights ----
        int gw = ((bid - GA - GB - GCONV) * 256 + t) >> 6;   // 0..95
        int l  = t & 63;
        const float* W = (gw < 32) ? Wl : (gw < 64) ? Wr : Wp;
        unsigned short* O = (gw < 32) ? WlB : (gw < 64) ? WrB : WpB;
        int ktnt = gw & 31, kt = ktnt >> 3, nt = ktnt & 7;
        bf16x8 v;
        #pragma unroll
        for (int j = 0; j < 8; ++j)
            v[j] = (short)f2bf(W[(size_t)(kt * 32 + (l >> 4) * 8 + j) * D + nt * 16 + (l & 15)]);
        *reinterpret_cast<bf16x8*>(O + ((size_t)ktnt * 64 + l) * 8) = v;
    }
}

// ---------------------------------------------------------------------------
// sort: per (type,bucket): entries -> LDS histogram + scan + scatter, persist
// sorted src list (ushort, coalesced) + per-node offsets for the gather pass.
// ---------------------------------------------------------------------------
__global__ __launch_bounds__(512)
void sort_kernel(const unsigned int* __restrict__ ent_a, const int* __restrict__ cnt_a,
                 const unsigned int* __restrict__ ent_b, const int* __restrict__ cnt_b,
                 unsigned short* __restrict__ srcl_g, int* __restrict__ off_g,
                 int NBKT, int CAP)
{
    extern __shared__ __align__(16) char smem_raw[];
    int* tmp  = (int*)smem_raw;                          // CAP
    int* off  = tmp + CAP;                               // BT+1
    int* cur  = off + BT + 1;                            // BT
    int* wtot = cur + BT;                                // 2
    unsigned short* srcl = (unsigned short*)(wtot + 2);  // CAP

    const int bid  = blockIdx.x;
    const int type = (bid >= NBKT);
    const int k    = bid - type * NBKT;
    const unsigned int* ent = type ? ent_b : ent_a;
    const int cnt = min((type ? cnt_b : cnt_a)[k], CAP);

    const int t = threadIdx.x, l = t & 63, w = t >> 6;

    if (t < BT) off[t] = 0;
    __syncthreads();

    for (int i = t; i < cnt; i += 512) {
        unsigned e = ent[(size_t)k * CAP + i];
        tmp[i] = (int)e;
        atomicAdd(&off[e & (BT - 1)], 1);
    }
    __syncthreads();

    int v = 0, s = 0;
    if (t < BT) {
        v = off[t]; s = v;
        #pragma unroll
        for (int o = 1; o < 64; o <<= 1) {
            int u = __shfl_up(s, o, 64);
            if (l >= o) s += u;
        }
        if (l == 63) wtot[w] = s;
    }
    __syncthreads();
    if (t < BT) {
        int ex = ((w == 1) ? wtot[0] : 0) + s - v;
        off[t] = ex; cur[t] = ex;
    }
    if (t == 0) off[BT] = wtot[0] + wtot[1];
    __syncthreads();

    for (int i = t; i < cnt; i += 512) {
        unsigned e = (unsigned)tmp[i];
        int pos = atomicAdd(&cur[e & (BT - 1)], 1);
        srcl[pos] = (unsigned short)(e >> 7);
    }
    __syncthreads();

    for (int i = t; i < cnt; i += 512)
        srcl_g[(size_t)bid * CAP + i] = srcl[i];
    if (t <= BT)
        off_g[(size_t)bid * (BT + 1) + t] = off[t];
}

// ---------------------------------------------------------------------------
// gather: grid = 4 slices x 2 types x NBKT.  slice = bid & 3 -> each XCD
// touches ONE 3.2 MB slice (L2-resident; FETCH confirmed 21 MB in r5).
// VALU fix vs r5: 32-bit element index into a UNIFORM uint* base (saddr
// global_load, 1 v_lshl_add per load instead of per-lane 64-bit math) and
// f32x2 accumulate (v_pk_add_f32).
// ---------------------------------------------------------------------------
__global__ __launch_bounds__(256)
void gather_kernel(const unsigned short* __restrict__ x_bfs,
                   const unsigned short* __restrict__ srcl_g,
                   const int* __restrict__ off_g,
                   unsigned short* __restrict__ mean_a_s,
                   unsigned short* __restrict__ mean_b_s,
                   int N, int NBKT, int CAP)
{
    extern __shared__ __align__(16) char smem_raw[];
    int* off = (int*)smem_raw;                               // BT+1
    unsigned short* srcl = (unsigned short*)(off + BT + 1);  // CAP

    const int bid   = blockIdx.x;
    const int slice = bid & 3;
    const int tb    = bid >> 2;                // (type,bucket)
    const int type  = (tb >= NBKT);
    const int k     = tb - type * NBKT;

    const int t = threadIdx.x, l = t & 63, w = t >> 6;
    const int q = l >> 4;                      // edge subgroup 0..3
    const unsigned c = l & 15;                 // dword within 16-dword slice row

    const int cnt = off_g[(size_t)tb * (BT + 1) + BT];
    for (int i = t; i <= BT; i += 256)
        off[i] = off_g[(size_t)tb * (BT + 1) + i];
    for (int i = t; i < cnt; i += 256)
        srcl[i] = srcl_g[(size_t)tb * CAP + i];
    __syncthreads();

    const unsigned* xs = (const unsigned*)(x_bfs + (size_t)slice * N * 32);
    unsigned short* mean = (type ? mean_b_s : mean_a_s) + (size_t)slice * N * 32;

    for (int tt = w; tt < BT; tt += 4) {
        const int n = k * BT + tt;
        if (n >= N) break;
        const int o0 = off[tt], o1 = off[tt + 1];
        f32x2 acc = {0.f, 0.f};

        int j = o0 + q;
        for (; j + 4 < o1; j += 8) {
            unsigned i0 = ((unsigned)srcl[j] << 4) + c;      // 32-bit elem idx
            unsigned i1 = ((unsigned)srcl[j + 4] << 4) + c;
            unsigned v0 = xs[i0];
            unsigned v1 = xs[i1];
            f32x2 u0, u1;
            u0[0] = __builtin_bit_cast(float, v0 << 16);
            u0[1] = __builtin_bit_cast(float, v0 & 0xffff0000u);
            u1[0] = __builtin_bit_cast(float, v1 << 16);
            u1[1] = __builtin_bit_cast(float, v1 & 0xffff0000u);
            acc += u0 + u1;
        }
        if (j < o1) {
            unsigned v0 = xs[((unsigned)srcl[j] << 4) + c];
            f32x2 u0;
            u0[0] = __builtin_bit_cast(float, v0 << 16);
            u0[1] = __builtin_bit_cast(float, v0 & 0xffff0000u);
            acc += u0;
        }

        acc[0] += __shfl_xor(acc[0], 16, 64);
        acc[0] += __shfl_xor(acc[0], 32, 64);
        acc[1] += __shfl_xor(acc[1], 16, 64);
        acc[1] += __shfl_xor(acc[1], 32, 64);

        float r = 1.0f / fmaxf((float)(o1 - o0), 1.0f);
        if (q == 0) {
            unsigned o = ((unsigned)f2bf(acc[1] * r) << 16) | f2bf(acc[0] * r);
            *(unsigned*)(mean + (size_t)n * 32 + c * 2) = o;
        }
    }
}

// ---------------------------------------------------------------------------
// MFMA GEMM (round-3 structure; A-fragment loads slice-major).
// ---------------------------------------------------------------------------
__global__ __launch_bounds__(256)
void gemm_kernel(const unsigned short* __restrict__ mean_a_s,
                 const unsigned short* __restrict__ mean_b_s,
                 const unsigned short* __restrict__ x_bfs,
                 const unsigned short* __restrict__ WlB,
                 const unsigned short* __restrict__ WrB,
                 const unsigned short* __restrict__ WpB,
                 const float* __restrict__ bl, const float* __restrict__ bp,
                 float* __restrict__ out, int N)
{
    __shared__ unsigned short hA[64 * D];
    __shared__ unsigned short hB[64 * D];

    const int t = threadIdx.x, w = t >> 6, l = t & 63;
    const int q = l & 15;
    const int kg = l >> 4;
    const int node0 = blockIdx.x * 64 + w * 16;
    const int arow = min(node0 + q, N - 1);

    bf16x8 fa[4], fb[4], fx[4];
    #pragma unroll
    for (int kt = 0; kt < 4; ++kt) {
        size_t o = ((size_t)kt * N + arow) * 32 + kg * 8;   // slice kt
        fa[kt] = *reinterpret_cast<const bf16x8*>(mean_a_s + o);
        fb[kt] = *reinterpret_cast<const bf16x8*>(mean_b_s + o);
        fx[kt] = *reinterpret_cast<const bf16x8*>(x_bfs + o);
    }

    #pragma unroll
    for (int nt = 0; nt < 8; ++nt) {
        f32x4 ca = {0.f, 0.f, 0.f, 0.f};
        f32x4 cb = {0.f, 0.f, 0.f, 0.f};
        #pragma unroll
        for (int kt = 0; kt < 4; ++kt) {
            const size_t fo = ((size_t)(kt * 8 + nt) * 64 + l) * 8;
            bf16x8 wl = *reinterpret_cast<const bf16x8*>(WlB + fo);
            bf16x8 wr = *reinterpret_cast<const bf16x8*>(WrB + fo);
            ca = MFMA16(fa[kt], wl, ca, 0, 0, 0);
            ca = MFMA16(fx[kt], wr, ca, 0, 0, 0);
            cb = MFMA16(fb[kt], wl, cb, 0, 0, 0);
            cb = MFMA16(fx[kt], wr, cb, 0, 0, 0);
        }
        float blv = bl[nt * 16 + q];
        #pragma unroll
        for (int r = 0; r < 4; ++r) {
            int lrow = w * 16 + kg * 4 + r;
            int byte = lrow * 256 + (nt * 16 + q) * 2;
            byte ^= ((lrow & 7) << 4);
            *reinterpret_cast<unsigned short*>(reinterpret_cast<char*>(hA) + byte) = f2bf(ca[r] + blv);
            *reinterpret_cast<unsigned short*>(reinterpret_cast<char*>(hB) + byte) = f2bf(cb[r] + blv);
        }
    }
    __syncthreads();

    bf16x8 ga[4], gb[4];
    #pragma unroll
    for (int kt = 0; kt < 4; ++kt) {
        int lrow = w * 16 + q;
        int byte = lrow * 256 + kt * 64 + kg * 16;
        byte ^= ((lrow & 7) << 4);
        ga[kt] = *reinterpret_cast<bf16x8*>(reinterpret_cast<char*>(hA) + byte);
        gb[kt] = *reinterpret_cast<bf16x8*>(reinterpret_cast<char*>(hB) + byte);
    }

    f32x4 la[8], lb[8];
    #pragma unroll
    for (int nt = 0; nt < 8; ++nt) {
        la[nt] = f32x4{0.f, 0.f, 0.f, 0.f};
        lb[nt] = f32x4{0.f, 0.f, 0.f, 0.f};
        #pragma unroll
        for (int kt = 0; kt < 4; ++kt) {
            const size_t fo = ((size_t)(kt * 8 + nt) * 64 + l) * 8;
            bf16x8 wp = *reinterpret_cast<const bf16x8*>(WpB + fo);
            la[nt] = MFMA16(ga[kt], wp, la[nt], 0, 0, 0);
            lb[nt] = MFMA16(gb[kt], wp, lb[nt], 0, 0, 0);
        }
        float bpv = bp[nt * 16 + q];
        #pragma unroll
        for (int r = 0; r < 4; ++r) { la[nt][r] += bpv; lb[nt][r] += bpv; }
    }

    #pragma unroll
    for (int r = 0; r < 4; ++r) {
        float ma = -INFINITY, mb = -INFINITY;
        #pragma unroll
        for (int nt = 0; nt < 8; ++nt) {
            ma = fmaxf(ma, la[nt][r]);
            mb = fmaxf(mb, lb[nt][r]);
        }
        #pragma unroll
        for (int o = 1; o < 16; o <<= 1) {
            ma = fmaxf(ma, __shfl_xor(ma, o, 64));
            mb = fmaxf(mb, __shfl_xor(mb, o, 64));
        }
        float ea[8], eb[8], sa = 0.f, sb = 0.f;
        #pragma unroll
        for (int nt = 0; nt < 8; ++nt) {
            ea[nt] = __expf(la[nt][r] - ma); sa += ea[nt];
            eb[nt] = __expf(lb[nt][r] - mb); sb += eb[nt];
        }
        #pragma unroll
        for (int o = 1; o < 16; o <<= 1) {
            sa += __shfl_xor(sa, o, 64);
            sb += __shfl_xor(sb, o, 64);
        }
        float ra = 0.5f / sa, rb = 0.5f / sb;
        int grow = node0 + kg * 4 + r;
        if (grow < N) {
            float* o = out + (size_t)grow * D + q;
            #pragma unroll
            for (int nt = 0; nt < 8; ++nt)
                o[nt * 16] = ea[nt] * ra + eb[nt] * rb;
        }
    }
}

// ---------------------------------------------------------------------------
extern "C" void kernel_launch(void* const* d_in, const int* in_sizes, int n_in,
                              void* d_out, int out_size, void* d_ws, size_t ws_size,
                              hipStream_t stream)
{
    const float* x  = (const float*)d_in[0];
    const float* Wl = (const float*)d_in[1];
    const float* bl = (const float*)d_in[2];
    const float* Wr = (const float*)d_in[3];
    const float* Wp = (const float*)d_in[4];
    const float* bp = (const float*)d_in[5];
    const int*   ea = (const int*)d_in[6];
    const int*   eb = (const int*)d_in[7];

    const int N  = in_sizes[0] / D;
    const int Ea = in_sizes[6] / 2;
    const int Eb = in_sizes[7] / 2;

    const int NBKT = (N + BT - 1) / BT;
    const int Emax = Ea > Eb ? Ea : Eb;
    int CAP = (int)(((long long)Emax * BT / N) * 5 / 4 + 128);
    CAP = (CAP + 7) & ~7;

    unsigned int* ent_a = (unsigned int*)d_ws;              // NBKT*CAP
    unsigned int* ent_b = ent_a + (size_t)NBKT * CAP;
    int* cnt_a = (int*)(ent_b + (size_t)NBKT * CAP);        // NBKT
    int* cnt_b = cnt_a + NBKT;
    int* off_g = cnt_b + NBKT;                              // 2*NBKT*(BT+1)
    uintptr_t p = (uintptr_t)(off_g + (size_t)2 * NBKT * (BT + 1));
    p = (p + 15) & ~(uintptr_t)15;
    unsigned short* srcl_g  = (unsigned short*)p;           // 2*NBKT*CAP
    unsigned short* x_bfs   = srcl_g + (size_t)2 * NBKT * CAP;
    unsigned short* mean_a_s = x_bfs + (size_t)N * D;
    unsigned short* mean_b_s = mean_a_s + (size_t)N * D;
    unsigned short* WlB     = mean_b_s + (size_t)N * D;
    unsigned short* WrB     = WlB + D * D;
    unsigned short* WpB     = WrB + D * D;

    hipMemsetAsync(cnt_a, 0, sizeof(int) * 2 * (size_t)NBKT, stream);

    const int GA = (Ea + TILE - 1) / TILE;
    const int GB = (Eb + TILE - 1) / TILE;
    const int GCONV = 512;
    prep_kernel<<<GA + GB + GCONV + 24, 256, 0, stream>>>(
        x, x_bfs, ea, Ea, eb, Eb, ent_a, cnt_a, ent_b, cnt_b,
        Wl, Wr, Wp, WlB, WrB, WpB, N, NBKT, CAP, GA, GB, GCONV);

    const int smem_sort = CAP * 6 + (BT + 1 + BT + 2) * 4 + 16;
    sort_kernel<<<2 * NBKT, 512, smem_sort, stream>>>(
        ent_a, cnt_a, ent_b, cnt_b, srcl_g, off_g, NBKT, CAP);

    const int smem_gather = (BT + 1) * 4 + CAP * 2 + 16;
    gather_kernel<<<8 * NBKT, 256, smem_gather, stream>>>(
        x_bfs, srcl_g, off_g, mean_a_s, mean_b_s, N, NBKT, CAP);

    gemm_kernel<<<(N + 63) / 64, 256, 0, stream>>>(
        mean_a_s, mean_b_s, x_bfs, WlB, WrB, WpB, bl, bp, (float*)d_out, N);
}